// Round 7
// baseline (19.199 us; speedup 1.0000x reference)
//
#include <hip/hip_runtime.h>
#include <math.h>

// Realspace Ewald: pot = 2 * sum_{i<j} q_i q_j erf(d_ij/sqrt(2))/d_ij * NORM/(4pi)
// N=6144. VALU-bound. erf via A&S 7.1.23 rational form (no exp2; absmax 0.0 in
// R6). One 64x64 triangle tile PER WAVE, 4 independent waves per block, zero
// __syncthreads: each wave stages its j-tile into a private LDS quadrant and
// broadcast-reads it. Tile id -> (ti,tj) via f32-sqrt closed form + fixup.

#if __has_builtin(__builtin_amdgcn_rsqf)
#define FRSQ(x) __builtin_amdgcn_rsqf(x)
#else
#define FRSQ(x) rsqrtf(x)
#endif
#if __has_builtin(__builtin_amdgcn_rcpf)
#define FRCP(x) __builtin_amdgcn_rcpf(x)
#else
#define FRCP(x) (1.0f / (x))
#endif

// A&S 7.1.23 coefficients pre-multiplied by (1/sqrt(2))^k so poly is in d:
#define B1 0.19685360f
#define B2 0.11519450f
#define B3 0.00034366f
#define B4 0.01952700f

template <bool CHECK>
__device__ __forceinline__ void pair_body(const float4 v, int k, int lane,
                                          float xi, float yi, float zi,
                                          float& acc) {
  float dx = xi - v.x;
  float dy = yi - v.y;
  float dz = zi - v.z;
  float d2 = fmaf(dx, dx, fmaf(dy, dy, dz * dz));
  float qk = v.w;
  if (CHECK) {
    bool take = (k > lane);  // diagonal tile: j>i <=> k>lane
    d2 = take ? d2 : 1.0f;
    qk = take ? qk : 0.0f;
  }
  float rinv = FRSQ(d2);
  float d = d2 * rinv;
  // erf(d/sqrt2) = 1 - 1/(1 + b1 d + b2 d^2 + b3 d^3 + b4 d^4)^4
  float poly = fmaf(fmaf(fmaf(B4, d, B3), d, B2), d, B1);
  poly = fmaf(poly, d, 1.0f);
  float y = FRCP(poly);
  float y2 = y * y;
  float y4 = y2 * y2;
  float w = fmaf(-y4, rinv, rinv);  // erf(d/sqrt2)/d
  acc = fmaf(qk, w, acc);
}

template <bool CHECK>
__device__ __forceinline__ float tile_sum(const float4* __restrict__ tile,
                                          int lane, float xi, float yi,
                                          float zi) {
  float acc0 = 0.f, acc1 = 0.f;
#pragma unroll 8
  for (int k = 0; k < 64; k += 2) {
    pair_body<CHECK>(tile[k], k, lane, xi, yi, zi, acc0);
    pair_body<CHECK>(tile[k + 1], k + 1, lane, xi, yi, zi, acc1);
  }
  return acc0 + acc1;
}

__global__ __launch_bounds__(256) void ewald_tri(
    const float* __restrict__ q, const float* __restrict__ r,
    float* __restrict__ partial, int n, int nt, int ntiles) {
  const int tid = threadIdx.x;
  const int lane = tid & 63;
  const int wid = tid >> 6;
  const int g = blockIdx.x * 4 + wid;  // global tile id (wave-uniform)
  if (g >= ntiles) return;

  // invert g -> (ti, tj), upper triangle incl. diagonal, row-major:
  // C(t) = t*nt - t*(t-1)/2 tiles before row t
  const float a = (float)nt + 0.5f;
  int ti = (int)(a - sqrtf(fmaf(a, a, -2.0f * (float)g)));
  if (ti < 0) ti = 0;
  if (ti >= nt) ti = nt - 1;
#define CUM(t) ((t) * nt - ((t) * ((t)-1)) / 2)
  while (CUM(ti + 1) <= g) ++ti;
  while (CUM(ti) > g) --ti;
  const int tj = ti + (g - CUM(ti));
#undef CUM

  const int ibeg = ti << 6;
  const int jbeg = tj << 6;

  // stage this wave's j-tile into its private LDS quadrant (no barriers:
  // same-wave ds ordering via lgkmcnt)
  __shared__ float4 tile[4][64];
  {
    int j = jbeg + lane;
    float4 v = make_float4(1e10f, 1e10f, 1e10f, 0.f);
    if (j < n) v = make_float4(r[3 * j], r[3 * j + 1], r[3 * j + 2], q[j]);
    tile[wid][lane] = v;
  }

  const int i = ibeg + lane;
  float qi = 0.f, xi = 1e10f, yi = 1e10f, zi = 1e10f;
  if (i < n) {
    qi = q[i];
    xi = r[3 * i];
    yi = r[3 * i + 1];
    zi = r[3 * i + 2];
  }

  float acc;
  if (ti == tj)
    acc = tile_sum<true>(tile[wid], lane, xi, yi, zi);
  else
    acc = tile_sum<false>(tile[wid], lane, xi, yi, zi);
  acc *= qi;

  // in-wave shfl reduce; lane 0 stores this tile's partial
  for (int m = 32; m > 0; m >>= 1) acc += __shfl_xor(acc, m, 64);
  if (lane == 0) partial[g] = acc;
}

__global__ __launch_bounds__(1024) void reduce_partials(
    const float* __restrict__ partial, float* __restrict__ out, int np,
    float scale) {
  const int tid = threadIdx.x;
  float acc = 0.f;
  for (int idx = tid; idx < np; idx += 1024) acc += partial[idx];
  for (int m = 32; m > 0; m >>= 1) acc += __shfl_xor(acc, m, 64);
  __shared__ float wsum[16];
  const int lane = tid & 63;
  const int wid = tid >> 6;
  if (lane == 0) wsum[wid] = acc;
  __syncthreads();
  if (tid == 0) {
    float s = 0.f;
    for (int w = 0; w < 16; ++w) s += wsum[w];
    out[0] = s * scale;
  }
}

extern "C" void kernel_launch(void* const* d_in, const int* in_sizes, int n_in,
                              void* d_out, int out_size, void* d_ws,
                              size_t ws_size, hipStream_t stream) {
  const float* q = (const float*)d_in[0];  // [N,1] fp32
  const float* r = (const float*)d_in[1];  // [N,3] fp32
  const int n = in_sizes[0];
  float* out = (float*)d_out;
  float* partial = (float*)d_ws;

  const int nt = (n + 63) / 64;              // 96 tiles per axis
  const int ntiles = nt * (nt + 1) / 2;      // 4656 triangle tiles
  const int nblocks = (ntiles + 3) / 4;      // 4 waves (tiles) per block

  ewald_tri<<<nblocks, 256, 0, stream>>>(q, r, partial, n, nt, ntiles);

  // 2 (triangle symmetry) * NORM/(2pi)/2 = NORM/(2pi)
  const float scale = (float)(90.0474 / (2.0 * M_PI));
  reduce_partials<<<1, 1024, 0, stream>>>(partial, out, ntiles, scale);
}